// Round 1
// 214.469 us; speedup vs baseline: 1.0200x; 1.0200x over previous
//
#include <hip/hip_runtime.h>
#include <hip/hip_bf16.h>

// Problem constants (from reference)
#define T_ROWS   8192
#define K_DIM    4096
#define N_INT    63
#define N_LEAF   64
#define NCLS     10

typedef __bf16 bf16x8 __attribute__((ext_vector_type(8)));
typedef __bf16 bf16x4 __attribute__((ext_vector_type(4)));
typedef float  f32x4  __attribute__((ext_vector_type(4)));

// ---------------------------------------------------------------------------
// Prep: W (63x4096 fp32) -> Wb (64x4096 bf16, row 63 zeroed); leaf_r[64]
// ---------------------------------------------------------------------------
__global__ __launch_bounds__(256) void sdt_prep(
    const float* __restrict__ W,
    const float* __restrict__ leaf_dist,
    const float* __restrict__ class_reward,
    __bf16* __restrict__ Wb,
    float* __restrict__ leaf_r)
{
    int gid  = blockIdx.x * 256 + threadIdx.x;   // 65536 threads total
    int base = gid * 4;                          // element idx in 64x4096
    int n    = base >> 12;                       // row (4096 per row)
    bf16x4 v;
    if (n < N_INT) {
        const float4 w = *reinterpret_cast<const float4*>(W + base);
        v[0] = (__bf16)w.x; v[1] = (__bf16)w.y; v[2] = (__bf16)w.z; v[3] = (__bf16)w.w;
    } else {
        v[0] = (__bf16)0.0f; v[1] = (__bf16)0.0f; v[2] = (__bf16)0.0f; v[3] = (__bf16)0.0f;
    }
    *reinterpret_cast<bf16x4*>(Wb + base) = v;

    if (blockIdx.x == 0 && threadIdx.x < N_LEAF) {
        int i = threadIdx.x;
        float m = -1e30f;
        #pragma unroll
        for (int j = 0; j < NCLS; ++j) m = fmaxf(m, leaf_dist[i * NCLS + j]);
        float s = 0.0f, d = 0.0f;
        #pragma unroll
        for (int j = 0; j < NCLS; ++j) {
            float e = expf(leaf_dist[i * NCLS + j] - m);
            s += e;
            d += e * class_reward[j];
        }
        leaf_r[i] = d / s;
    }
}

// ---------------------------------------------------------------------------
// Main: fused GEMM (bf16 MFMA) + sigmoid + tree propagation + reduce
// 512 blocks x 512 threads (8 waves). BM=16 rows/block, wave-split K (512 ea).
// v2: explicit software pipeline — A prefetched 2 iters ahead (3-stage reg
// rotation, HBM ~900 cyc), B prefetched 1 iter ahead (2-stage, L2 ~200 cyc).
// Stage indices are compile-time constants under full unroll (no scratch).
// ---------------------------------------------------------------------------
__global__ __launch_bounds__(512, 4) void sdt_main(
    const float* __restrict__ X,       // 8192 x 4096 fp32
    const __bf16* __restrict__ Wb,     // 64 x 4096 bf16
    const float* __restrict__ b,       // 63
    const float* __restrict__ beta,    // 63
    const float* __restrict__ leaf_r,  // 64
    float* __restrict__ out)           // scalar
{
    // Padded stride 65 breaks the 4-quad bank alias on the accumulator dump.
    __shared__ float red[8 * 16 * 65];   // per-wave C copies
    __shared__ float Pbuf[16 * 64];      // sigmoid'd node probs per row
    __shared__ float sred[8];

    const int tid  = threadIdx.x;
    const int wid  = tid >> 6;
    const int lane = tid & 63;
    const int m16  = lane & 15;          // A row within tile / C col
    const int q    = lane >> 4;          // quad

    const int row0 = blockIdx.x * 16;
    const int kbase = wid * (K_DIM / 8); // 512 K per wave

    // Per-lane base pointers; all per-iteration offsets are immediates.
    const float*  Ab = X  + (size_t)(row0 + m16) * K_DIM + kbase + q * 8;
    const __bf16* Bb = Wb + (size_t)m16 * K_DIM + kbase + q * 8;

    f32x4 acc[4];
    #pragma unroll
    for (int g = 0; g < 4; ++g) acc[g] = (f32x4){0.0f, 0.0f, 0.0f, 0.0f};

    // Pipeline register stages
    float4 pa0[3], pa1[3];   // A: [stage] -> 8 fp32 (one MFMA A-fragment)
    bf16x8 pb[2][4];         // B: [stage][g]

#define LDA(s, itv) do { \
        pa0[s] = *reinterpret_cast<const float4*>(Ab + (itv) * 32); \
        pa1[s] = *reinterpret_cast<const float4*>(Ab + (itv) * 32 + 4); \
    } while (0)
#define LDB(s, itv) do { \
        _Pragma("unroll") \
        for (int g = 0; g < 4; ++g) \
            pb[s][g] = *reinterpret_cast<const bf16x8*>( \
                Bb + (size_t)g * 16 * K_DIM + (itv) * 32); \
    } while (0)

    // Prologue: A for it=0,1; B for it=0.
    LDA(0, 0);
    LDA(1, 1);
    LDB(0, 0);

    #pragma unroll
    for (int it = 0; it < 16; ++it) {
        const int sa  = it % 3;          // current A stage
        const int sa2 = (it + 2) % 3;    // A stage being filled (it+2)
        const int sb  = it & 1;          // current B stage
        const int sbn = sb ^ 1;          // B stage being filled (it+1)

        // Issue next loads FIRST (deepest latency first).
        if (it < 14) LDA(sa2, it + 2);
        if (it < 15) LDB(sbn, it + 1);

        // Convert current A stage fp32 -> bf16 fragment.
        bf16x8 af;
        af[0] = (__bf16)pa0[sa].x; af[1] = (__bf16)pa0[sa].y;
        af[2] = (__bf16)pa0[sa].z; af[3] = (__bf16)pa0[sa].w;
        af[4] = (__bf16)pa1[sa].x; af[5] = (__bf16)pa1[sa].y;
        af[6] = (__bf16)pa1[sa].z; af[7] = (__bf16)pa1[sa].w;

        #pragma unroll
        for (int g = 0; g < 4; ++g)
            acc[g] = __builtin_amdgcn_mfma_f32_16x16x32_bf16(af, pb[sb][g], acc[g], 0, 0, 0);
    }
#undef LDA
#undef LDB

    // Dump per-wave partial C: C[row=q*4+r][col=g*16+m16]
    #pragma unroll
    for (int g = 0; g < 4; ++g)
        #pragma unroll
        for (int r = 0; r < 4; ++r)
            red[(wid * 16 + q * 4 + r) * 65 + g * 16 + m16] = acc[g][r];
    __syncthreads();

    // Reduce 8 wave copies -> logits -> P = sigmoid(beta*(l+b))
    for (int e = tid; e < 16 * 64; e += 512) {
        const int r = e >> 6, c = e & 63;
        float s = 0.0f;
        #pragma unroll
        for (int w = 0; w < 8; ++w) s += red[(w * 16 + r) * 65 + c];
        float P = 0.0f;
        if (c < N_INT) {
            const float z = beta[c] * (s + b[c]);
            P = 1.0f / (1.0f + __expf(-z));
        }
        Pbuf[r * 64 + c] = P;
    }
    __syncthreads();

    // Tree: thread -> (row = tid>>5, 2 leaves). leaf path product * leaf_r.
    const int row  = tid >> 5;
    const int pair = tid & 31;
    float score = 0.0f;
    #pragma unroll
    for (int u = 0; u < 2; ++u) {
        const int leaf = pair * 2 + u;
        float prod = 1.0f;
        #pragma unroll
        for (int k = 0; k < 6; ++k) {
            const int node = ((1 << k) - 1) + (leaf >> (6 - k));
            const float p  = Pbuf[row * 64 + node];
            const int bit  = (leaf >> (5 - k)) & 1;
            prod *= bit ? (1.0f - p) : p;
        }
        score += prod * leaf_r[leaf];
    }

    // Block reduction -> one atomicAdd per block
    #pragma unroll
    for (int off = 32; off > 0; off >>= 1)
        score += __shfl_down(score, off, 64);
    if (lane == 0) sred[wid] = score;
    __syncthreads();
    if (tid == 0) {
        float s = 0.0f;
        #pragma unroll
        for (int w = 0; w < 8; ++w) s += sred[w];
        atomicAdd(out, s);
    }
}

// ---------------------------------------------------------------------------
extern "C" void kernel_launch(void* const* d_in, const int* in_sizes, int n_in,
                              void* d_out, int out_size, void* d_ws, size_t ws_size,
                              hipStream_t stream)
{
    const float* X           = (const float*)d_in[0];
    const float* W           = (const float*)d_in[1];
    const float* b           = (const float*)d_in[2];
    const float* beta        = (const float*)d_in[3];
    const float* leaf_dist   = (const float*)d_in[4];
    const float* class_rew   = (const float*)d_in[5];
    float* out               = (float*)d_out;

    __bf16* Wb    = (__bf16*)d_ws;                                  // 64*4096*2 B
    float*  leafr = (float*)((char*)d_ws + (size_t)N_LEAF * K_DIM * 2);

    hipMemsetAsync(d_out, 0, sizeof(float), stream);                // ws/out are poisoned each replay
    sdt_prep<<<256, 256, 0, stream>>>(W, leaf_dist, class_rew, Wb, leafr);
    sdt_main<<<T_ROWS / 16, 512, 0, stream>>>(X, Wb, b, beta, leafr, out);
}

// Round 2
// 212.576 us; speedup vs baseline: 1.0291x; 1.0089x over previous
//
#include <hip/hip_runtime.h>
#include <hip/hip_bf16.h>

// Problem constants (from reference)
#define T_ROWS   8192
#define K_DIM    4096
#define N_INT    63
#define N_LEAF   64
#define NCLS     10

typedef __bf16 bf16x8 __attribute__((ext_vector_type(8)));
typedef __bf16 bf16x4 __attribute__((ext_vector_type(4)));
typedef float  f32x4  __attribute__((ext_vector_type(4)));

// ---------------------------------------------------------------------------
// Prep: W (63x4096 fp32) -> Wb (64x4096 bf16, row 63 zeroed); leaf_r[64];
// also zeroes the scalar output (stream-ordered before sdt_main).
// ---------------------------------------------------------------------------
__global__ __launch_bounds__(256) void sdt_prep(
    const float* __restrict__ W,
    const float* __restrict__ leaf_dist,
    const float* __restrict__ class_reward,
    __bf16* __restrict__ Wb,
    float* __restrict__ leaf_r,
    float* __restrict__ out)
{
    int gid  = blockIdx.x * 256 + threadIdx.x;   // 65536 threads total
    int base = gid * 4;                          // element idx in 64x4096
    int n    = base >> 12;                       // row (4096 per row)
    bf16x4 v;
    if (n < N_INT) {
        const float4 w = *reinterpret_cast<const float4*>(W + base);
        v[0] = (__bf16)w.x; v[1] = (__bf16)w.y; v[2] = (__bf16)w.z; v[3] = (__bf16)w.w;
    } else {
        v[0] = (__bf16)0.0f; v[1] = (__bf16)0.0f; v[2] = (__bf16)0.0f; v[3] = (__bf16)0.0f;
    }
    *reinterpret_cast<bf16x4*>(Wb + base) = v;

    if (gid == 0) *out = 0.0f;                   // replaces hipMemsetAsync

    if (blockIdx.x == 0 && threadIdx.x < N_LEAF) {
        int i = threadIdx.x;
        float m = -1e30f;
        #pragma unroll
        for (int j = 0; j < NCLS; ++j) m = fmaxf(m, leaf_dist[i * NCLS + j]);
        float s = 0.0f, d = 0.0f;
        #pragma unroll
        for (int j = 0; j < NCLS; ++j) {
            float e = expf(leaf_dist[i * NCLS + j] - m);
            s += e;
            d += e * class_reward[j];
        }
        leaf_r[i] = d / s;
    }
}

// ---------------------------------------------------------------------------
// Main: fused GEMM (bf16 MFMA) + sigmoid + tree propagation + reduce
// 512 blocks x 512 threads (8 waves). BM=16 rows/block, wave-split K (512 ea).
// v3: age-correct VMEM issue order. vmcnt counts IN-ORDER, so the wait for
// B(it) force-drains everything older. Therefore per iteration we issue
// B(it+2) BEFORE A(it+3): at the consume point of iter it, the newest 14
// loads (A(it+1),B(it+1),A(it+2),B(it+2),A(it+3)) stay in flight, giving
// A a true 3-iteration slack (HBM ~900cyc) and B a 2-iteration slack (L2).
// Stage indices are compile-time constants under full unroll (no scratch).
// ---------------------------------------------------------------------------
__global__ __launch_bounds__(512, 4) void sdt_main(
    const float* __restrict__ X,       // 8192 x 4096 fp32
    const __bf16* __restrict__ Wb,     // 64 x 4096 bf16
    const float* __restrict__ b,       // 63
    const float* __restrict__ beta,    // 63
    const float* __restrict__ leaf_r,  // 64
    float* __restrict__ out)           // scalar
{
    // Padded stride 65 breaks the 4-quad bank alias on the accumulator dump.
    __shared__ float red[8 * 16 * 65];   // per-wave C copies
    __shared__ float Pbuf[16 * 64];      // sigmoid'd node probs per row
    __shared__ float sred[8];

    const int tid  = threadIdx.x;
    const int wid  = tid >> 6;
    const int lane = tid & 63;
    const int m16  = lane & 15;          // A row within tile / C col
    const int q    = lane >> 4;          // quad

    const int row0 = blockIdx.x * 16;
    const int kbase = wid * (K_DIM / 8); // 512 K per wave

    // Per-lane base pointers; all per-iteration offsets are immediates.
    const float*  Ab = X  + (size_t)(row0 + m16) * K_DIM + kbase + q * 8;
    const __bf16* Bb = Wb + (size_t)m16 * K_DIM + kbase + q * 8;

    f32x4 acc[4];
    #pragma unroll
    for (int g = 0; g < 4; ++g) acc[g] = (f32x4){0.0f, 0.0f, 0.0f, 0.0f};

    // Pipeline register stages: A distance 3 (4 stages), B distance 2 (3 stages)
    float4 pa0[4], pa1[4];   // A: [stage] -> 8 fp32 (one MFMA A-fragment)
    bf16x8 pb[3][4];         // B: [stage][g]

#define LDA(s, itv) do { \
        pa0[s] = *reinterpret_cast<const float4*>(Ab + (itv) * 32); \
        pa1[s] = *reinterpret_cast<const float4*>(Ab + (itv) * 32 + 4); \
    } while (0)
#define LDB(s, itv) do { \
        _Pragma("unroll") \
        for (int g = 0; g < 4; ++g) \
            pb[s][g] = *reinterpret_cast<const bf16x8*>( \
                Bb + (size_t)g * 16 * K_DIM + (itv) * 32); \
    } while (0)

    // Prologue in age order A0 < B0 < A1 < B1 < A2, so the it=0 consume-wait
    // only forces A0,B0.
    LDA(0, 0);
    LDB(0, 0);
    LDA(1, 1);
    LDB(1, 1);
    LDA(2, 2);

    #pragma unroll
    for (int it = 0; it < 16; ++it) {
        const int sa  = it & 3;          // current A stage
        const int sa3 = (it + 3) & 3;    // A stage being filled (it+3)
        const int sb  = it % 3;          // current B stage
        const int sb2 = (it + 2) % 3;    // B stage being filled (it+2)

        // Issue next loads FIRST; B before A so the deep A prefetches stay
        // younger than the B the next consume waits on.
        if (it < 14) LDB(sb2, it + 2);
        if (it < 13) LDA(sa3, it + 3);

        // Convert current A stage fp32 -> bf16 fragment.
        bf16x8 af;
        af[0] = (__bf16)pa0[sa].x; af[1] = (__bf16)pa0[sa].y;
        af[2] = (__bf16)pa0[sa].z; af[3] = (__bf16)pa0[sa].w;
        af[4] = (__bf16)pa1[sa].x; af[5] = (__bf16)pa1[sa].y;
        af[6] = (__bf16)pa1[sa].z; af[7] = (__bf16)pa1[sa].w;

        #pragma unroll
        for (int g = 0; g < 4; ++g)
            acc[g] = __builtin_amdgcn_mfma_f32_16x16x32_bf16(af, pb[sb][g], acc[g], 0, 0, 0);
    }
#undef LDA
#undef LDB

    // Dump per-wave partial C: C[row=q*4+r][col=g*16+m16]
    #pragma unroll
    for (int g = 0; g < 4; ++g)
        #pragma unroll
        for (int r = 0; r < 4; ++r)
            red[(wid * 16 + q * 4 + r) * 65 + g * 16 + m16] = acc[g][r];
    __syncthreads();

    // Reduce 8 wave copies -> logits -> P = sigmoid(beta*(l+b))
    for (int e = tid; e < 16 * 64; e += 512) {
        const int r = e >> 6, c = e & 63;
        float s = 0.0f;
        #pragma unroll
        for (int w = 0; w < 8; ++w) s += red[(w * 16 + r) * 65 + c];
        float P = 0.0f;
        if (c < N_INT) {
            const float z = beta[c] * (s + b[c]);
            P = 1.0f / (1.0f + __expf(-z));
        }
        Pbuf[r * 64 + c] = P;
    }
    __syncthreads();

    // Tree: thread -> (row = tid>>5, 2 leaves). leaf path product * leaf_r.
    const int row  = tid >> 5;
    const int pair = tid & 31;
    float score = 0.0f;
    #pragma unroll
    for (int u = 0; u < 2; ++u) {
        const int leaf = pair * 2 + u;
        float prod = 1.0f;
        #pragma unroll
        for (int k = 0; k < 6; ++k) {
            const int node = ((1 << k) - 1) + (leaf >> (6 - k));
            const float p  = Pbuf[row * 64 + node];
            const int bit  = (leaf >> (5 - k)) & 1;
            prod *= bit ? (1.0f - p) : p;
        }
        score += prod * leaf_r[leaf];
    }

    // Block reduction -> one atomicAdd per block
    #pragma unroll
    for (int off = 32; off > 0; off >>= 1)
        score += __shfl_down(score, off, 64);
    if (lane == 0) sred[wid] = score;
    __syncthreads();
    if (tid == 0) {
        float s = 0.0f;
        #pragma unroll
        for (int w = 0; w < 8; ++w) s += sred[w];
        atomicAdd(out, s);
    }
}

// ---------------------------------------------------------------------------
extern "C" void kernel_launch(void* const* d_in, const int* in_sizes, int n_in,
                              void* d_out, int out_size, void* d_ws, size_t ws_size,
                              hipStream_t stream)
{
    const float* X           = (const float*)d_in[0];
    const float* W           = (const float*)d_in[1];
    const float* b           = (const float*)d_in[2];
    const float* beta        = (const float*)d_in[3];
    const float* leaf_dist   = (const float*)d_in[4];
    const float* class_rew   = (const float*)d_in[5];
    float* out               = (float*)d_out;

    __bf16* Wb    = (__bf16*)d_ws;                                  // 64*4096*2 B
    float*  leafr = (float*)((char*)d_ws + (size_t)N_LEAF * K_DIM * 2);

    sdt_prep<<<256, 256, 0, stream>>>(W, leaf_dist, class_rew, Wb, leafr, out);
    sdt_main<<<T_ROWS / 16, 512, 0, stream>>>(X, Wb, b, beta, leafr, out);
}